// Round 10
// baseline (684.076 us; speedup 1.0000x reference)
//
#include <hip/hip_runtime.h>

// ---- problem constants ----
#define NXg    512
#define Sg     262144          // 512*512
#define NFRg   60
// ---- temporal blocking ----
#define Kg     12              // steps per chunk
#define NCHUNK 20              // 240 / 12
#define Tg     32              // owned tile (32x32), 16x16 tiles = 256 blocks
#define Eg     56              // extended tile (T + 2K)
#define EJP    58              // LDS row pitch in float2 (464 B -> odd group shift)
#define NSEGR  14              // 4-cell segments per row
#define NTHR   896             // 56 rows(+pad) ... = 64 rows*14? no: 64*14; see map
#define NPAIR  (Eg * (Eg / 2)) // 1568 float4 staging quads

// Zero the A-set state (cur+prev float2 = Sg float4 total).
// B-set is fully overwritten by chunk 0 before being read.
__global__ __launch_bounds__(512)
void cfrp_init(float4* __restrict__ ws4)
{
    const int gt = (int)blockIdx.x * 512 + (int)threadIdx.x;  // 262144
    ws4[gt] = make_float4(0.f, 0.f, 0.f, 0.f);
}

// one-cell update (float2 = {ux,uy})
#define CELLSTEP(nv, NW, N, NE, Wt, C, Et, SW, S, SE, P, GF)                 \
{                                                                            \
    const float sxx_x = N.x + S.x - 2.0f * C.x;                              \
    const float syy_x = Wt.x + Et.x - 2.0f * C.x;                            \
    const float sxy_x = 0.25f * (NW.x - NE.x - SW.x + SE.x);                 \
    const float sxx_y = N.y + S.y - 2.0f * C.y;                              \
    const float syy_y = Wt.y + Et.y - 2.0f * C.y;                            \
    const float sxy_y = 0.25f * (NW.y - NE.y - SW.y + SE.y);                 \
    const float lux = kc11 * sxx_x + kc66 * syy_x + kc1266 * sxy_y           \
                    + kc16x2 * sxy_x + kc16 * sxx_y + kc26 * syy_y;          \
    const float luy = kc66 * sxx_y + kc22 * syy_y + kc1266 * sxy_x           \
                    + kc16 * sxx_x + kc26 * syy_x + kc26x2 * sxy_y           \
                    + fa * GF;                                               \
    nv = make_float2(2.0f * C.x - P.x + lux, 2.0f * C.y - P.y + luy);        \
}

// Advance 12 timesteps. Interleaved float2 LDS, pitch 58; double-buffered,
// one barrier per step. Thread owns a 1x4 strip; centers + u_{t-1} in regs.
// 896 threads: row = tid/16, seg = tid&15 (segs 14,15 idle -> 56x14 strips).
__global__ __launch_bounds__(NTHR)
void cfrp_chunk(const float* __restrict__ lc11, const float* __restrict__ lc22,
                const float* __restrict__ lc12, const float* __restrict__ lc16,
                const float* __restrict__ lc26, const float* __restrict__ lc66,
                const float* __restrict__ rho_p, const float* __restrict__ sig,
                const float* __restrict__ gauss, float* __restrict__ out,
                const float2* __restrict__ gcur, const float2* __restrict__ gprev,
                float2* __restrict__ ncur, float2* __restrict__ nprev,
                int TB)
{
    __shared__ float2 sf[2][Eg * EJP];

    const int tid = (int)threadIdx.x;
    // XCD-affinity: XCD q (= wg&7 round-robin heuristic) owns tile-rows 2q..2q+1.
    const int w  = (int)blockIdx.x;
    const int q  = w & 7;
    const int r_ = w >> 3;                 // 0..31
    const int ti = q * 2 + (r_ >> 4);      // 0..15
    const int tj = r_ & 15;                // 0..15
    const int oi = ti * Tg - Kg;
    const int oj = tj * Tg - Kg;

    // uniform material constants
    const float C11 = fminf(fmaxf(expf(lc11[0]), 1e9f), 1e13f);
    const float C22 = fminf(fmaxf(expf(lc22[0]), 1e9f), 1e13f);
    const float C12 = fminf(fmaxf(expf(lc12[0]), 1e9f), 1e13f);
    const float C16 = fminf(fmaxf(expf(lc16[0]), 1e9f), 1e13f);
    const float C26 = fminf(fmaxf(expf(lc26[0]), 1e9f), 1e13f);
    const float C66 = fminf(fmaxf(expf(lc66[0]), 1e9f), 1e13f);
    const float rh   = rho_p[0];
    const float dt2  = 2.5e-15f;
    const float kk   = dt2 * 1e6f / rh;
    const float kc11 = kk * C11, kc22 = kk * C22, kc66 = kk * C66;
    const float kc16 = kk * C16, kc26 = kk * C26;
    const float kc1266 = kk * (C12 + C66);
    const float kc16x2 = 2.0f * kc16;
    const float kc26x2 = 2.0f * kc26;
    const float gsc = dt2 / rh;

    // ---- stage u_t into both LDS buffers (float4 = 2 float2 cells) ----
    #pragma unroll
    for (int s = 0; s < 2; ++s) {
        const int p = tid + s * NTHR;          // 0..1791; need 0..1567
        if (p < NPAIR) {
            const int rr  = p / (Eg / 2);      // 0..55
            const int cc2 = (p - rr * (Eg / 2)) * 2;   // even f2 col 0..54
            const int gi  = oi + rr;
            const int gj  = oj + cc2;          // even
            float4 v = make_float4(0.f, 0.f, 0.f, 0.f);
            if (((unsigned)gi < NXg) && ((unsigned)gj < NXg))
                v = *(const float4*)&gcur[gi * NXg + gj];
            const int d = rr * EJP + cc2;
            *(float4*)&sf[0][d] = v;
            *(float4*)&sf[1][d] = v;
        }
    }
    // zero the 2-float2 row pads (cols 56,57), both buffers
    if (tid < Eg) {
        const int d = tid * EJP + Eg;
        *(float4*)&sf[0][d] = make_float4(0.f, 0.f, 0.f, 0.f);
        *(float4*)&sf[1][d] = make_float4(0.f, 0.f, 0.f, 0.f);
    }

    // ---- per-strip setup (row = tid/16, seg = tid&15; segs 0..13 live) ----
    const int  srow = tid >> 4;
    const int  scol = tid & 15;
    const bool act  = (scol < NSEGR) && (srow >= 1) && (srow <= Eg - 2);
    const int  c0   = scol * 4;
    const int  gi   = oi + srow;
    const int  gj0  = oj + c0;                 // multiple of 4 -> quad in/out
    const int  dC   = srow * EJP + c0;
    const bool in4  = ((unsigned)gi < NXg) && (gj0 >= 0) && (gj0 < (int)NXg);
    const bool own  = act && (srow >= Kg) && (srow < Kg + Tg)
                          && (scol >= 3) && (scol <= 10);
    const int  go0  = gi * NXg + gj0;

    float2 pv0 = {0,0}, pv1 = {0,0}, pv2 = {0,0}, pv3 = {0,0};
    float  gf0 = 0.f, gf1 = 0.f, gf2 = 0.f, gf3 = 0.f;
    if (act && in4) {
        const float4 t0 = *(const float4*)&gprev[go0];
        const float4 t1 = *(const float4*)&gprev[go0 + 2];
        pv0 = make_float2(t0.x, t0.y); pv1 = make_float2(t0.z, t0.w);
        pv2 = make_float2(t1.x, t1.y); pv3 = make_float2(t1.z, t1.w);
        const float4 g = *(const float4*)&gauss[go0];
        gf0 = g.x * gsc; gf1 = g.y * gsc; gf2 = g.z * gsc; gf3 = g.w * gsc;
    }
    __syncthreads();

    float2 cv0, cv1, cv2, cv3;
    {
        const float4 a = *(const float4*)&sf[0][dC];
        const float4 b = *(const float4*)&sf[0][dC + 2];
        cv0 = make_float2(a.x, a.y); cv1 = make_float2(a.z, a.w);
        cv2 = make_float2(b.x, b.y); cv3 = make_float2(b.z, b.w);
    }

    const float2* cur = sf[0];
    float2*       nxt = sf[1];

    #pragma unroll
    for (int st = 0; st < Kg; ++st) {
        const float fa = sig[TB + st];
        if (act) {
            const int iT = dC - EJP;
            const int iB = dC + EJP;
            const float4 t01 = *(const float4*)&cur[iT];
            const float4 t23 = *(const float4*)&cur[iT + 2];
            const float2 twv = cur[iT - 1];
            const float2 tev = cur[iT + 4];
            const float4 b01 = *(const float4*)&cur[iB];
            const float4 b23 = *(const float4*)&cur[iB + 2];
            const float2 bwv = cur[iB - 1];
            const float2 bev = cur[iB + 4];
            const float2 wmv = cur[dC - 1];
            const float2 emv = cur[dC + 4];

            const float2 ta0 = twv, ta1 = make_float2(t01.x, t01.y),
                         ta2 = make_float2(t01.z, t01.w),
                         ta3 = make_float2(t23.x, t23.y),
                         ta4 = make_float2(t23.z, t23.w), ta5 = tev;
            const float2 ba0 = bwv, ba1 = make_float2(b01.x, b01.y),
                         ba2 = make_float2(b01.z, b01.w),
                         ba3 = make_float2(b23.x, b23.y),
                         ba4 = make_float2(b23.z, b23.w), ba5 = bev;

            float2 nv0, nv1, nv2, nv3;
            CELLSTEP(nv0, ta0, ta1, ta2, wmv, cv0, cv1, ba0, ba1, ba2, pv0, gf0)
            CELLSTEP(nv1, ta1, ta2, ta3, cv0, cv1, cv2, ba1, ba2, ba3, pv1, gf1)
            CELLSTEP(nv2, ta2, ta3, ta4, cv1, cv2, cv3, ba2, ba3, ba4, pv2, gf2)
            CELLSTEP(nv3, ta3, ta4, ta5, cv2, cv3, emv, ba3, ba4, ba5, pv3, gf3)

            if (!in4) {     // out-of-domain quad stays 0 (zero padding BC)
                nv0 = nv1 = nv2 = nv3 = make_float2(0.f, 0.f);
            }
            pv0 = cv0; pv1 = cv1; pv2 = cv2; pv3 = cv3;
            cv0 = nv0; cv1 = nv1; cv2 = nv2; cv3 = nv3;

            *(float4*)&nxt[dC]     = make_float4(cv0.x, cv0.y, cv1.x, cv1.y);
            *(float4*)&nxt[dC + 2] = make_float4(cv2.x, cv2.y, cv3.x, cv3.y);

            if (((st & 3) == 0) && own) {      // frames at st = 0, 4, 8
                const int fr = (TB + st) >> 2;
                *(float4*)&out[fr * Sg + go0] =
                    make_float4(cv0.x, cv1.x, cv2.x, cv3.x);
                *(float4*)&out[(fr + NFRg) * Sg + go0] =
                    make_float4(cv0.y, cv1.y, cv2.y, cv3.y);
            }
        }
        __syncthreads();
        float2* tmp = (float2*)cur; cur = nxt; nxt = tmp;
    }

    // handoff from registers (owned 32x32 per block, disjoint across blocks)
    if (own) {
        *(float4*)&ncur[go0]      = make_float4(cv0.x, cv0.y, cv1.x, cv1.y);
        *(float4*)&ncur[go0 + 2]  = make_float4(cv2.x, cv2.y, cv3.x, cv3.y);
        *(float4*)&nprev[go0]     = make_float4(pv0.x, pv0.y, pv1.x, pv1.y);
        *(float4*)&nprev[go0 + 2] = make_float4(pv2.x, pv2.y, pv3.x, pv3.y);
    }
}

extern "C" void kernel_launch(void* const* d_in, const int* in_sizes, int n_in,
                              void* d_out, int out_size, void* d_ws, size_t ws_size,
                              hipStream_t stream) {
    const float* lc11  = (const float*)d_in[0];
    const float* lc22  = (const float*)d_in[1];
    const float* lc12  = (const float*)d_in[2];
    const float* lc16  = (const float*)d_in[3];
    const float* lc26  = (const float*)d_in[4];
    const float* lc66  = (const float*)d_in[5];
    const float* rho_p = (const float*)d_in[6];
    const float* sig   = (const float*)d_in[7];
    const float* gauss = (const float*)d_in[8];
    float* out  = (float*)d_out;
    float2* ws2 = (float2*)d_ws;

    // A-set: [cur, prev], B-set: [cur, prev] (float2 planes, Sg cells each)
    float2* Ac = ws2;           float2* Ap = ws2 + Sg;
    float2* Bc = ws2 + 2 * Sg;  float2* Bp = ws2 + 3 * Sg;

    hipLaunchKernelGGL(cfrp_init, dim3(512), dim3(512), 0, stream, (float4*)d_ws);

    for (int c = 0; c < NCHUNK; ++c) {
        float2 *rc, *rp, *wc, *wp;
        if (c & 1) { rc = Bc; rp = Bp; wc = Ac; wp = Ap; }
        else       { rc = Ac; rp = Ap; wc = Bc; wp = Bp; }
        hipLaunchKernelGGL(cfrp_chunk, dim3(256), dim3(NTHR), 0, stream,
                           lc11, lc22, lc12, lc16, lc26, lc66, rho_p, sig,
                           gauss, out, rc, rp, wc, wp, c * Kg);
    }
}

// Round 11
// 548.484 us; speedup vs baseline: 1.2472x; 1.2472x over previous
//
#include <hip/hip_runtime.h>

// ---- problem constants ----
#define NXg    512
#define Sg     262144          // 512*512
#define NFRg   60
// ---- temporal blocking ----
#define Kg     8               // steps per chunk
#define NCHUNK 30              // 240 / 8
#define Tg     32              // owned tile (32x32), 16x16 tiles = 256 blocks
#define Eg     48              // extended tile (T + 2K)
#define EJP    50              // padded LDS row stride in float2 (400 B)
#define NSEGR  12              // 4-cell segments per row
#define NTHR   576             // 48 rows * 12 segments = 9 waves
#define NWAVE  9

// Zero the A-set state (cur+prev float2 = Sg float4 total).
// B-set is fully overwritten by chunk 0 before being read.
__global__ __launch_bounds__(512)
void cfrp_init(float4* __restrict__ ws4)
{
    const int gt = (int)blockIdx.x * 512 + (int)threadIdx.x;  // 262144
    ws4[gt] = make_float4(0.f, 0.f, 0.f, 0.f);
}

// one-cell update (float2 = {ux,uy})
#define CELLSTEP(nv, NW, N, NE, Wt, C, Et, SW, S, SE, P, GF)                 \
{                                                                            \
    const float sxx_x = N.x + S.x - 2.0f * C.x;                              \
    const float syy_x = Wt.x + Et.x - 2.0f * C.x;                            \
    const float sxy_x = 0.25f * (NW.x - NE.x - SW.x + SE.x);                 \
    const float sxx_y = N.y + S.y - 2.0f * C.y;                              \
    const float syy_y = Wt.y + Et.y - 2.0f * C.y;                            \
    const float sxy_y = 0.25f * (NW.y - NE.y - SW.y + SE.y);                 \
    const float lux = kc11 * sxx_x + kc66 * syy_x + kc1266 * sxy_y           \
                    + kc16x2 * sxy_x + kc16 * sxx_y + kc26 * syy_y;          \
    const float luy = kc66 * sxx_y + kc22 * syy_y + kc1266 * sxy_x           \
                    + kc16 * sxx_x + kc26 * syy_x + kc26x2 * sxy_y           \
                    + fa * GF;                                               \
    nv = make_float2(2.0f * C.x - P.x + lux, 2.0f * C.y - P.y + luy);        \
}

// Advance 8 timesteps. Identical to the 548us R7 kernel EXCEPT the per-step
// __syncthreads is replaced by neighbor-wave flag sync (time-skewed waves).
// Wave w owns a ~5-6 row band; step st only requires waves w+-1 at flag>=st
// (this also guarantees they finished READING buf[(st+1)&1], which w is
// about to overwrite: neighbor's step st-1 reads buf[(st-1)&1]=same buf).
__global__ __launch_bounds__(NTHR)
void cfrp_chunk(const float* __restrict__ lc11, const float* __restrict__ lc22,
                const float* __restrict__ lc12, const float* __restrict__ lc16,
                const float* __restrict__ lc26, const float* __restrict__ lc66,
                const float* __restrict__ rho_p, const float* __restrict__ sig,
                const float* __restrict__ gauss, float* __restrict__ out,
                const float2* __restrict__ gcur, const float2* __restrict__ gprev,
                float2* __restrict__ ncur, float2* __restrict__ nprev,
                int TB)
{
    __shared__ float2 sf[2][Eg * EJP];
    __shared__ int sflag[NWAVE * 16];       // 64B-strided wave step counters

    const int tid = (int)threadIdx.x;
    const int wv  = tid >> 6;               // wave 0..8 (rows band)
    // XCD-affinity: XCD q (= wg&7 round-robin heuristic) owns tile-rows 2q..2q+1.
    const int w  = (int)blockIdx.x;
    const int q  = w & 7;
    const int r_ = w >> 3;                 // 0..31
    const int ti = q * 2 + (r_ >> 4);      // 0..15
    const int tj = r_ & 15;                // 0..15
    const int oi = ti * Tg - Kg;
    const int oj = tj * Tg - Kg;

    // uniform material constants
    const float C11 = fminf(fmaxf(expf(lc11[0]), 1e9f), 1e13f);
    const float C22 = fminf(fmaxf(expf(lc22[0]), 1e9f), 1e13f);
    const float C12 = fminf(fmaxf(expf(lc12[0]), 1e9f), 1e13f);
    const float C16 = fminf(fmaxf(expf(lc16[0]), 1e9f), 1e13f);
    const float C26 = fminf(fmaxf(expf(lc26[0]), 1e9f), 1e13f);
    const float C66 = fminf(fmaxf(expf(lc66[0]), 1e9f), 1e13f);
    const float rh   = rho_p[0];
    const float dt2  = 2.5e-15f;
    const float kk   = dt2 * 1e6f / rh;
    const float kc11 = kk * C11, kc22 = kk * C22, kc66 = kk * C66;
    const float kc16 = kk * C16, kc26 = kk * C26;
    const float kc1266 = kk * (C12 + C66);
    const float kc16x2 = 2.0f * kc16;
    const float kc26x2 = 2.0f * kc26;
    const float gsc = dt2 / rh;

    // ---- stage u_t into both LDS buffers (float4 = 2 float2 cells) ----
    #pragma unroll
    for (int s = 0; s < 2; ++s) {
        const int p  = tid + s * NTHR;       // 0..1151 cell pairs (48 x 24)
        const int rr = p / 24;
        const int cp = (p - rr * 24) * 2;    // even ext f2 col
        const int gi = oi + rr;
        const int gj = oj + cp;
        float4 v = make_float4(0.f, 0.f, 0.f, 0.f);
        if (((unsigned)gi < NXg) && ((unsigned)gj < NXg))
            v = *(const float4*)&gcur[gi * NXg + gj];
        const int li = rr * EJP + cp;
        *(float4*)&sf[0][li] = v;
        *(float4*)&sf[1][li] = v;
    }
    // zero the 2-float2 row pads (cols 48,49), both buffers
    if (tid < Eg) {
        const int li = tid * EJP + Eg;
        *(float4*)&sf[0][li] = make_float4(0.f, 0.f, 0.f, 0.f);
        *(float4*)&sf[1][li] = make_float4(0.f, 0.f, 0.f, 0.f);
    }
    if (tid < NWAVE) sflag[tid * 16] = 0;

    // ---- per-strip setup (1x4 cells per thread) ----
    const int  srow = tid / NSEGR;
    const int  scol = tid - srow * NSEGR;
    const bool act  = (srow >= 1) && (srow <= Eg - 2);
    const int  c0   = scol * 4;
    const int  gi   = oi + srow;
    const int  gj0  = oj + c0;               // multiple of 4 -> quad all in/out
    const int  dC   = srow * EJP + c0;
    const bool in4  = ((unsigned)gi < NXg) && (gj0 >= 0) && (gj0 < (int)NXg);
    const bool own  = (srow >= Kg) && (srow < Kg + Tg) && (scol >= 2) && (scol <= 9);
    const int  go0  = gi * NXg + gj0;

    float2 pv0 = {0,0}, pv1 = {0,0}, pv2 = {0,0}, pv3 = {0,0};
    float  gf0 = 0.f, gf1 = 0.f, gf2 = 0.f, gf3 = 0.f;
    if (act && in4) {
        const float4 t0 = *(const float4*)&gprev[go0];
        const float4 t1 = *(const float4*)&gprev[go0 + 2];
        pv0 = make_float2(t0.x, t0.y); pv1 = make_float2(t0.z, t0.w);
        pv2 = make_float2(t1.x, t1.y); pv3 = make_float2(t1.z, t1.w);
        const float4 g = *(const float4*)&gauss[go0];
        gf0 = g.x * gsc; gf1 = g.y * gsc; gf2 = g.z * gsc; gf3 = g.w * gsc;
    }
    __syncthreads();   // staging + flag init visible to all waves

    float2 cv0, cv1, cv2, cv3;
    {
        const float4 a = *(const float4*)&sf[0][dC];
        const float4 b = *(const float4*)&sf[0][dC + 2];
        cv0 = make_float2(a.x, a.y); cv1 = make_float2(a.z, a.w);
        cv2 = make_float2(b.x, b.y); cv3 = make_float2(b.z, b.w);
    }

    const float2* cur = sf[0];
    float2*       nxt = sf[1];

    #pragma unroll
    for (int st = 0; st < Kg; ++st) {
        // ---- wait for adjacent row-band waves to reach step st ----
        if (st > 0) {
            if (wv > 0) {
                while (__hip_atomic_load(&sflag[(wv - 1) * 16],
                                         __ATOMIC_ACQUIRE,
                                         __HIP_MEMORY_SCOPE_WORKGROUP) < st)
                    __builtin_amdgcn_s_sleep(1);
            }
            if (wv < NWAVE - 1) {
                while (__hip_atomic_load(&sflag[(wv + 1) * 16],
                                         __ATOMIC_ACQUIRE,
                                         __HIP_MEMORY_SCOPE_WORKGROUP) < st)
                    __builtin_amdgcn_s_sleep(1);
            }
        }

        const float fa = sig[TB + st];
        if (act) {
            const int iT = dC - EJP;
            const int iB = dC + EJP;
            const float4 t01 = *(const float4*)&cur[iT];
            const float4 t23 = *(const float4*)&cur[iT + 2];
            const float2 twv = cur[iT - 1];
            const float2 tev = cur[iT + 4];
            const float4 b01 = *(const float4*)&cur[iB];
            const float4 b23 = *(const float4*)&cur[iB + 2];
            const float2 bwv = cur[iB - 1];
            const float2 bev = cur[iB + 4];
            const float2 wmv = cur[dC - 1];
            const float2 emv = cur[dC + 4];

            const float2 ta0 = twv, ta1 = make_float2(t01.x, t01.y),
                         ta2 = make_float2(t01.z, t01.w),
                         ta3 = make_float2(t23.x, t23.y),
                         ta4 = make_float2(t23.z, t23.w), ta5 = tev;
            const float2 ba0 = bwv, ba1 = make_float2(b01.x, b01.y),
                         ba2 = make_float2(b01.z, b01.w),
                         ba3 = make_float2(b23.x, b23.y),
                         ba4 = make_float2(b23.z, b23.w), ba5 = bev;

            float2 nv0, nv1, nv2, nv3;
            CELLSTEP(nv0, ta0, ta1, ta2, wmv, cv0, cv1, ba0, ba1, ba2, pv0, gf0)
            CELLSTEP(nv1, ta1, ta2, ta3, cv0, cv1, cv2, ba1, ba2, ba3, pv1, gf1)
            CELLSTEP(nv2, ta2, ta3, ta4, cv1, cv2, cv3, ba2, ba3, ba4, pv2, gf2)
            CELLSTEP(nv3, ta3, ta4, ta5, cv2, cv3, emv, ba3, ba4, ba5, pv3, gf3)

            if (!in4) {     // out-of-domain quad stays 0 (zero padding BC)
                nv0 = nv1 = nv2 = nv3 = make_float2(0.f, 0.f);
            }
            pv0 = cv0; pv1 = cv1; pv2 = cv2; pv3 = cv3;
            cv0 = nv0; cv1 = nv1; cv2 = nv2; cv3 = nv3;

            *(float4*)&nxt[dC]     = make_float4(cv0.x, cv0.y, cv1.x, cv1.y);
            *(float4*)&nxt[dC + 2] = make_float4(cv2.x, cv2.y, cv3.x, cv3.y);

            if (((st & 3) == 0) && own) {      // frames at st = 0, 4
                const int fr = (TB + st) >> 2;
                *(float4*)&out[fr * Sg + go0] =
                    make_float4(cv0.x, cv1.x, cv2.x, cv3.x);
                *(float4*)&out[(fr + NFRg) * Sg + go0] =
                    make_float4(cv0.y, cv1.y, cv2.y, cv3.y);
            }
        }
        // ---- publish this wave's step completion (release orders ds_writes) ----
        if ((tid & 63) == 0) {
            __hip_atomic_store(&sflag[wv * 16], st + 1,
                               __ATOMIC_RELEASE, __HIP_MEMORY_SCOPE_WORKGROUP);
        }
        float2* tmp = (float2*)cur; cur = nxt; nxt = tmp;
    }

    // handoff from registers (owned 32x32 per block, disjoint across blocks)
    if (own) {
        *(float4*)&ncur[go0]      = make_float4(cv0.x, cv0.y, cv1.x, cv1.y);
        *(float4*)&ncur[go0 + 2]  = make_float4(cv2.x, cv2.y, cv3.x, cv3.y);
        *(float4*)&nprev[go0]     = make_float4(pv0.x, pv0.y, pv1.x, pv1.y);
        *(float4*)&nprev[go0 + 2] = make_float4(pv2.x, pv2.y, pv3.x, pv3.y);
    }
}

extern "C" void kernel_launch(void* const* d_in, const int* in_sizes, int n_in,
                              void* d_out, int out_size, void* d_ws, size_t ws_size,
                              hipStream_t stream) {
    const float* lc11  = (const float*)d_in[0];
    const float* lc22  = (const float*)d_in[1];
    const float* lc12  = (const float*)d_in[2];
    const float* lc16  = (const float*)d_in[3];
    const float* lc26  = (const float*)d_in[4];
    const float* lc66  = (const float*)d_in[5];
    const float* rho_p = (const float*)d_in[6];
    const float* sig   = (const float*)d_in[7];
    const float* gauss = (const float*)d_in[8];
    float* out  = (float*)d_out;
    float2* ws2 = (float2*)d_ws;

    // A-set: [cur, prev], B-set: [cur, prev] (float2 planes, Sg cells each)
    float2* Ac = ws2;           float2* Ap = ws2 + Sg;
    float2* Bc = ws2 + 2 * Sg;  float2* Bp = ws2 + 3 * Sg;

    hipLaunchKernelGGL(cfrp_init, dim3(512), dim3(512), 0, stream, (float4*)d_ws);

    for (int c = 0; c < NCHUNK; ++c) {
        float2 *rc, *rp, *wc, *wp;
        if (c & 1) { rc = Bc; rp = Bp; wc = Ac; wp = Ap; }
        else       { rc = Ac; rp = Ap; wc = Bc; wp = Bp; }
        hipLaunchKernelGGL(cfrp_chunk, dim3(256), dim3(NTHR), 0, stream,
                           lc11, lc22, lc12, lc16, lc26, lc66, rho_p, sig,
                           gauss, out, rc, rp, wc, wp, c * Kg);
    }
}